// Round 5
// baseline (524.736 us; speedup 1.0000x reference)
//
#include <hip/hip_runtime.h>

#define QX_OFF    8388608
#define LOSS_OFF  8519680
#define MARGIN_V  0.05f          // on v = (d2 - ||x||^2)/2 scale -> 0.1 on d2 (validated: 0.0625)

typedef __attribute__((ext_vector_type(8))) short bf16x8;
typedef __attribute__((ext_vector_type(4))) float f32x4;
typedef unsigned long long u64;

static __device__ __forceinline__ unsigned short rne_bf16(float f) {
    unsigned u = __float_as_uint(f);
    u += 0x7FFFu + ((u >> 16) & 1u);
    return (unsigned short)(u >> 16);
}
static __device__ __forceinline__ float bf16_to_f(unsigned short h) {
    return __uint_as_float(((unsigned)h) << 16);
}
static __device__ __forceinline__ u64 pack4(unsigned short a, unsigned short b,
                                            unsigned short c, unsigned short d) {
    return (u64)a | ((u64)b << 16) | ((u64)c << 32) | ((u64)d << 48);
}

// ---------------- prep: exact norms (round-1 expression), PRE-SWIZZLED bf16-split codebook ----
// lutbf row c (256 B): 16B-granule gg stored at byte c*256 + ((gg*16) ^ ((c&7)<<4));
// gg 0..7 = high parts (dims 8*gg..8*gg+7), gg 8..15 = low parts.
__global__ void vq_prep_kernel(const float* __restrict__ lut,
                               float* __restrict__ norms,
                               char* __restrict__ lutbfB,
                               int* __restrict__ flagcnt,
                               float* __restrict__ d_out) {
    int c = blockIdx.x * 256 + threadIdx.x;
    if (c == 0) { d_out[LOSS_OFF] = 0.f; *flagcnt = 0; }
    if (c < 1024) {
        const float4* c4 = reinterpret_cast<const float4*>(lut + c * 64);
        float s = 0.f;
        u64 hq[16], lq[16];
#pragma unroll
        for (int i = 0; i < 16; ++i) {
            float4 v = c4[i];
            s += v.x * v.x + v.y * v.y + v.z * v.z + v.w * v.w;   // verbatim round-1 (exact path)
            unsigned short h0 = rne_bf16(v.x), h1 = rne_bf16(v.y),
                           h2 = rne_bf16(v.z), h3 = rne_bf16(v.w);
            unsigned short l0 = rne_bf16(v.x - bf16_to_f(h0)), l1 = rne_bf16(v.y - bf16_to_f(h1)),
                           l2 = rne_bf16(v.z - bf16_to_f(h2)), l3 = rne_bf16(v.w - bf16_to_f(h3));
            hq[i] = pack4(h0, h1, h2, h3);
            lq[i] = pack4(l0, l1, l2, l3);
        }
        norms[c] = s;
        char* base = lutbfB + c * 256;
        const int swz = (c & 7) << 4;
#pragma unroll
        for (int gg = 0; gg < 8; ++gg) {
            u64* dh = reinterpret_cast<u64*>(base + ((gg * 16) ^ swz));
            dh[0] = hq[2 * gg]; dh[1] = hq[2 * gg + 1];
            u64* dl = reinterpret_cast<u64*>(base + (((8 + gg) * 16) ^ swz));
            dl[0] = lq[2 * gg]; dl[1] = lq[2 * gg + 1];
        }
    }
}

// ---------------- screen: register-resident A, LDS-streamed B, packed argmin ----------------
// Block: 64 tokens, 4 waves; wave w owns code-tiles {2w, 2w+1} per 128-code chunk.
// LDS: A 16 KB (then reused as reduce scratch) | B double-buffer 2x32 KB = 81920 B total.
__launch_bounds__(256, 2)
__global__ void vq_screen_kernel(const float* __restrict__ x,
                                 const uint4* __restrict__ lutbf4,
                                 const float* __restrict__ norms,
                                 float* __restrict__ qxf,
                                 int* __restrict__ flaglist,
                                 int* __restrict__ flagcnt) {
    extern __shared__ char smc[];                 // [0,16384): A ; [16384,81920): B dbuf
    const int tid  = threadIdx.x;
    const int w    = tid >> 6, lane = tid & 63;
    const int lcol = lane & 15, g = lane >> 4;
    const int g16  = g << 4;
    const int t0   = blockIdx.x * 64;
    const long xbase = (long)(t0 >> 12) * 262144 + (t0 & 4095);

    // ---- stage A: negated bf16-split x, swizzled rows (read once -> conflicts negligible) ----
#pragma unroll
    for (int i = 0; i < 4; ++i) {
        int item = tid + 256 * i;                 // 0..1023
        int t = item & 63, q = item >> 6;         // q = d-quad 0..15
        const float* xp = x + xbase + (long)(4 * q) * 4096 + t;
        float v0 = xp[0], v1 = xp[4096], v2 = xp[8192], v3 = xp[12288];
        unsigned short h0 = rne_bf16(v0), h1 = rne_bf16(v1), h2 = rne_bf16(v2), h3 = rne_bf16(v3);
        unsigned short l0 = rne_bf16(v0 - bf16_to_f(h0)), l1 = rne_bf16(v1 - bf16_to_f(h1)),
                       l2 = rne_bf16(v2 - bf16_to_f(h2)), l3 = rne_bf16(v3 - bf16_to_f(h3));
        u64 ph = pack4(h0, h1, h2, h3) ^ 0x8000800080008000ULL;   // A = -x (exact sign flip)
        u64 pl = pack4(l0, l1, l2, l3) ^ 0x8000800080008000ULL;
        int rowb = t * 256, swz = (t & 7) << 4;
        *reinterpret_cast<u64*>(smc + rowb + ((q * 8) ^ swz)) = ph;
        *reinterpret_cast<u64*>(smc + rowb + ((128 + q * 8) ^ swz)) = pl;
    }

    // issue chunk-0 B loads into staging regs (latency hidden under A work)
    uint4 streg[8];
#pragma unroll
    for (int i = 0; i < 8; ++i) streg[i] = lutbf4[w * 512 + i * 64 + lane];

    __syncthreads();                              // A visible

    // ---- A -> registers: 4 token-tiles x 6 k-steps (96 VGPR) ----
    constexpr int KA2[6] = {0, 64, 0, 64, 128, 192};
    constexpr int KB2[6] = {0, 64, 128, 192, 0, 64};
    const int aswz = (lcol & 7) << 4;
    bf16x8 areg[4][6];
#pragma unroll
    for (int tt = 0; tt < 4; ++tt) {
        const char* arow = smc + (tt * 16 + lcol) * 256;
#pragma unroll
        for (int s = 0; s < 6; ++s)
            areg[tt][s] = *reinterpret_cast<const bf16x8*>(arow + ((KA2[s] + g16) ^ aswz));
    }

    // per-lane C-init values: 128 + ||c||^2 / 2 for this lane's 2 codes per chunk
    float cni[8][2];
#pragma unroll
    for (int ch = 0; ch < 8; ++ch)
#pragma unroll
        for (int c = 0; c < 2; ++c)
            cni[ch][c] = 128.f + 0.5f * norms[ch * 128 + (w * 2 + c) * 16 + lcol];

    char* B0 = smc + 16384;
    char* B1 = smc + 16384 + 32768;
    // write chunk0, prefetch chunk1
#pragma unroll
    for (int i = 0; i < 8; ++i)
        *reinterpret_cast<uint4*>(B0 + w * 8192 + i * 1024 + lane * 16) = streg[i];
#pragma unroll
    for (int i = 0; i < 8; ++i) streg[i] = lutbf4[2048 + w * 512 + i * 64 + lane];
    __syncthreads();                              // B0 ready

    const unsigned VMASK = 0xFFFFFC00u;
    unsigned m1[4][4], m2[4][4];
#pragma unroll
    for (int tt = 0; tt < 4; ++tt)
#pragma unroll
        for (int r = 0; r < 4; ++r) { m1[tt][r] = 0xFFFFFFFFu; m2[tt][r] = 0xFFFFFFFFu; }

    const unsigned idbase = (unsigned)(w * 32 + lcol);
    const int bswz = (lcol & 7) << 4;

#pragma unroll
    for (int ch = 0; ch < 8; ++ch) {
        const char* cur = (ch & 1) ? B1 : B0;
        char* oth = (ch & 1) ? B0 : B1;

        f32x4 acc[4][2];
#pragma unroll
        for (int tt = 0; tt < 4; ++tt)
#pragma unroll
            for (int c = 0; c < 2; ++c) {
                float v = cni[ch][c];
                acc[tt][c] = (f32x4){v, v, v, v};
            }

        const char* brow0 = cur + (w * 32 + lcol) * 256;
        const char* brow1 = brow0 + 16 * 256;
#pragma unroll
        for (int s = 0; s < 6; ++s) {
            bf16x8 b0 = *reinterpret_cast<const bf16x8*>(brow0 + ((KB2[s] + g16) ^ bswz));
            bf16x8 b1 = *reinterpret_cast<const bf16x8*>(brow1 + ((KB2[s] + g16) ^ bswz));
#pragma unroll
            for (int tt = 0; tt < 4; ++tt) {
                acc[tt][0] = __builtin_amdgcn_mfma_f32_16x16x32_bf16(areg[tt][s], b0, acc[tt][0], 0, 0, 0);
                acc[tt][1] = __builtin_amdgcn_mfma_f32_16x16x32_bf16(areg[tt][s], b1, acc[tt][1], 0, 0, 0);
            }
        }

        // packed argmin tracking: 4 VALU per candidate, index in 10 LSBs
        const unsigned idc0 = idbase + (unsigned)(ch * 128);
        const unsigned idc1 = idc0 + 16u;
#pragma unroll
        for (int tt = 0; tt < 4; ++tt)
#pragma unroll
            for (int r = 0; r < 4; ++r) {
                unsigned v0 = (__float_as_uint(acc[tt][0][r]) & VMASK) | idc0;
                unsigned v1 = (__float_as_uint(acc[tt][1][r]) & VMASK) | idc1;
                unsigned mm = m1[tt][r], ss = m2[tt][r];
                ss = min(ss, max(mm, v0)); mm = min(mm, v0);
                ss = min(ss, max(mm, v1)); mm = min(mm, v1);
                m1[tt][r] = mm; m2[tt][r] = ss;
            }

        // T14 async-stage: write next chunk, then issue chunk+2 loads
        if (ch < 7) {
#pragma unroll
            for (int i = 0; i < 8; ++i)
                *reinterpret_cast<uint4*>(oth + w * 8192 + i * 1024 + lane * 16) = streg[i];
        }
        if (ch < 6) {
#pragma unroll
            for (int i = 0; i < 8; ++i)
                streg[i] = lutbf4[(ch + 2) * 2048 + w * 512 + i * 64 + lane];
        }
        __syncthreads();
    }

    // ---- merge 16 lanes (lcol) holding disjoint code subsets ----
#pragma unroll
    for (int m = 1; m <= 8; m <<= 1) {
#pragma unroll
        for (int tt = 0; tt < 4; ++tt)
#pragma unroll
            for (int r = 0; r < 4; ++r) {
                unsigned o1 = __shfl_xor(m1[tt][r], m, 64);
                unsigned o2 = __shfl_xor(m2[tt][r], m, 64);
                unsigned n1 = min(m1[tt][r], o1);
                m2[tt][r] = min(min(m2[tt][r], o2), max(m1[tt][r], o1));
                m1[tt][r] = n1;
            }
    }

    // ---- cross-wave merge via LDS (A region is dead -> reuse) ----
    unsigned* red = reinterpret_cast<unsigned*>(smc);      // [4 waves][64 tokens][2]
    if (lcol == 0) {
#pragma unroll
        for (int tt = 0; tt < 4; ++tt)
#pragma unroll
            for (int r = 0; r < 4; ++r) {
                int t = tt * 16 + g * 4 + r;
                red[(w * 64 + t) * 2]     = m1[tt][r];
                red[(w * 64 + t) * 2 + 1] = m2[tt][r];
            }
    }
    __syncthreads();
    if (tid < 64) {
        unsigned a1 = red[tid * 2], a2 = red[tid * 2 + 1];
#pragma unroll
        for (int ww = 1; ww < 4; ++ww) {
            unsigned b1 = red[(ww * 64 + tid) * 2], b2 = red[(ww * 64 + tid) * 2 + 1];
            unsigned n1 = min(a1, b1);
            a2 = min(min(a2, b2), max(a1, b1));
            a1 = n1;
        }
        int token = t0 + tid;
        qxf[token] = (float)(a1 & 1023u);
        float gap = __uint_as_float(a2 & VMASK) - __uint_as_float(a1 & VMASK);
        if (gap <= MARGIN_V) {
            int slot = atomicAdd(flagcnt, 1);
            flaglist[slot] = token;
        }
    }
}

// ---------------- rescan: exact full scan per flagged token (verbatim exact association) ----
__global__ void vq_rescan_kernel(const float* __restrict__ x,
                                 const float* __restrict__ lut,
                                 const float* __restrict__ norms,
                                 float* __restrict__ qxf,
                                 const int* __restrict__ flaglist,
                                 const int* __restrict__ flagcnt) {
    __shared__ float sx[64];
    __shared__ float rv[256];
    __shared__ int   ri[256];
    const int tid = threadIdx.x;
    const int cnt = *flagcnt;

    for (int idx = blockIdx.x; idx < cnt; idx += gridDim.x) {
        int t = flaglist[idx];
        __syncthreads();                           // protect sx/rv reuse
        if (tid < 64)
            sx[tid] = x[(long)(t >> 12) * 262144 + (t & 4095) + (long)tid * 4096];
        __syncthreads();
        const float4* sx4 = reinterpret_cast<const float4*>(sx);

        float bv = 3.4e38f; int bi = 0;
#pragma unroll
        for (int j0 = 0; j0 < 4; ++j0) {
            int j = tid * 4 + j0;                  // ascending per thread
            const float4* cf4 = reinterpret_cast<const float4*>(lut + j * 64);
            float acc = 0.f;
#pragma unroll
            for (int s = 0; s < 16; ++s) {
                float4 cf = cf4[s], xf = sx4[s];
                acc += xf.x * cf.x + xf.y * cf.y + xf.z * cf.z + xf.w * cf.w;  // verbatim
            }
            float v = norms[j] - 2.f * acc;        // verbatim
            if (v < bv) { bv = v; bi = j; }
        }
        rv[tid] = bv; ri[tid] = bi;
        __syncthreads();
#pragma unroll
        for (int off = 128; off >= 1; off >>= 1) {
            if (tid < off) {
                float ov = rv[tid + off]; int oi = ri[tid + off];
                if (ov < rv[tid] || (ov == rv[tid] && oi < ri[tid])) { rv[tid] = ov; ri[tid] = oi; }
            }
            __syncthreads();
        }
        if (tid == 0) qxf[t] = (float)ri[0];
    }
}

// ---------------- epilogue: out = 2x - x_e (float4), loss ----------------
__global__ void vq_epilogue_kernel(const float* __restrict__ x,
                                   const float* __restrict__ lut,
                                   float* __restrict__ d_out) {
    __shared__ float cs[8192];                     // [d][128 tokens]
    __shared__ int qsh[128];
    const int tid = threadIdx.x;
    const int t0 = blockIdx.x * 128;
    const long xbase = (long)(t0 >> 12) * 262144 + (t0 & 4095);

    if (tid < 128) qsh[tid] = (int)d_out[QX_OFF + t0 + tid];
    __syncthreads();
    {
        int t = tid >> 1, half = tid & 1;
        int q = qsh[t];
        const float4* src = reinterpret_cast<const float4*>(lut + q * 64 + half * 32);
#pragma unroll
        for (int k = 0; k < 8; ++k) {
            float4 v = src[k];
            int dbase = half * 32 + k * 4;
            cs[(dbase + 0) * 128 + t] = v.x;
            cs[(dbase + 1) * 128 + t] = v.y;
            cs[(dbase + 2) * 128 + t] = v.z;
            cs[(dbase + 3) * 128 + t] = v.w;
        }
    }
    __syncthreads();

    float lsum = 0.f;
    {
        int t4 = (tid & 31) * 4, db = tid >> 5;    // 4 consecutive tokens, dim stride 8
#pragma unroll
        for (int it = 0; it < 8; ++it) {
            int d = it * 8 + db;
            float4 xv = *reinterpret_cast<const float4*>(x + xbase + (long)d * 4096 + t4);
            float4 cv = *reinterpret_cast<const float4*>(cs + d * 128 + t4);
            float4 ov;
            ov.x = 2.f * xv.x - cv.x; ov.y = 2.f * xv.y - cv.y;
            ov.z = 2.f * xv.z - cv.z; ov.w = 2.f * xv.w - cv.w;
            *reinterpret_cast<float4*>(d_out + xbase + (long)d * 4096 + t4) = ov;
            float e0 = xv.x - cv.x, e1 = xv.y - cv.y, e2 = xv.z - cv.z, e3 = xv.w - cv.w;
            lsum += e0 * e0 + e1 * e1 + e2 * e2 + e3 * e3;
        }
    }
#pragma unroll
    for (int off = 32; off >= 1; off >>= 1)
        lsum += __shfl_down(lsum, off, 64);
    if ((tid & 63) == 0)
        atomicAdd(&d_out[LOSS_OFF], lsum * (1.25f / 8388608.f));
}

extern "C" void kernel_launch(void* const* d_in, const int* in_sizes, int n_in,
                              void* d_out, int out_size, void* d_ws, size_t ws_size,
                              hipStream_t stream) {
    const float* x   = (const float*)d_in[0];   // [32,64,64,64] f32
    const float* lut = (const float*)d_in[1];   // [1024,64] f32
    float* out = (float*)d_out;
    char* ws = (char*)d_ws;
    float* norms   = (float*)ws;                         // 4 KB
    char*  lutbfB  = ws + 4096;                          // 256 KB pre-swizzled bf16-split
    int*   flagcnt = (int*)(ws + 266240);
    int*   flaglist= (int*)(ws + 266256);                // worst case 512 KB

    vq_prep_kernel<<<4, 256, 0, stream>>>(lut, norms, lutbfB, flagcnt, out);
    vq_screen_kernel<<<2048, 256, 81920, stream>>>(x, (const uint4*)lutbfB, norms,
                                                   out + QX_OFF, flaglist, flagcnt);
    vq_rescan_kernel<<<1024, 256, 0, stream>>>(x, lut, norms, out + QX_OFF,
                                               flaglist, flagcnt);
    vq_epilogue_kernel<<<1024, 256, 0, stream>>>(x, lut, out);
}

// Round 6
// 422.825 us; speedup vs baseline: 1.2410x; 1.2410x over previous
//
#include <hip/hip_runtime.h>

#define QX_OFF    8388608
#define LOSS_OFF  8519680
#define MARGIN_D2 0.03125f   // gap threshold on d^2 scale; analytic 2*delta bound ~3.4e-3 -> 9x headroom

typedef __attribute__((ext_vector_type(8))) short bf16x8;
typedef __attribute__((ext_vector_type(4))) float f32x4;
typedef unsigned long long u64;

static __device__ __forceinline__ unsigned short rne_bf16(float f) {
    unsigned u = __float_as_uint(f);
    u += 0x7FFFu + ((u >> 16) & 1u);
    return (unsigned short)(u >> 16);
}
static __device__ __forceinline__ float bf16_to_f(unsigned short h) {
    return __uint_as_float(((unsigned)h) << 16);
}
static __device__ __forceinline__ u64 pack4(unsigned short a, unsigned short b,
                                            unsigned short c, unsigned short d) {
    return (u64)a | ((u64)b << 16) | ((u64)c << 32) | ((u64)d << 48);
}

// ---------------- prep: exact norms (verbatim round-1 expr), pre-swizzled bf16-split codebook ----
// lutbf row c (256 B): 16B-granule gg at byte c*256 + ((gg*16) ^ ((c&7)<<4));
// gg 0..7 = high halves (dims 8gg..8gg+7), gg 8..15 = low halves.
__global__ void vq_prep_kernel(const float* __restrict__ lut,
                               float* __restrict__ norms,
                               char* __restrict__ lutbfB,
                               int* __restrict__ flagcnt,
                               float* __restrict__ d_out) {
    int c = blockIdx.x * 256 + threadIdx.x;
    if (c == 0) { d_out[LOSS_OFF] = 0.f; *flagcnt = 0; }
    if (c < 1024) {
        const float4* c4 = reinterpret_cast<const float4*>(lut + c * 64);
        float s = 0.f;
        u64 hq[16], lq[16];
#pragma unroll
        for (int i = 0; i < 16; ++i) {
            float4 v = c4[i];
            s += v.x * v.x + v.y * v.y + v.z * v.z + v.w * v.w;   // verbatim (exact path)
            unsigned short h0 = rne_bf16(v.x), h1 = rne_bf16(v.y),
                           h2 = rne_bf16(v.z), h3 = rne_bf16(v.w);
            unsigned short l0 = rne_bf16(v.x - bf16_to_f(h0)), l1 = rne_bf16(v.y - bf16_to_f(h1)),
                           l2 = rne_bf16(v.z - bf16_to_f(h2)), l3 = rne_bf16(v.w - bf16_to_f(h3));
            hq[i] = pack4(h0, h1, h2, h3);
            lq[i] = pack4(l0, l1, l2, l3);
        }
        norms[c] = s;
        char* base = lutbfB + c * 256;
        const int swz = (c & 7) << 4;
#pragma unroll
        for (int gg = 0; gg < 8; ++gg) {
            u64* dh = reinterpret_cast<u64*>(base + ((gg * 16) ^ swz));
            dh[0] = hq[2 * gg]; dh[1] = hq[2 * gg + 1];
            u64* dl = reinterpret_cast<u64*>(base + (((8 + gg) * 16) ^ swz));
            dl[0] = lq[2 * gg]; dl[1] = lq[2 * gg + 1];
        }
    }
}

// ---------------- screen + fused epilogue ----------------
// 128 tokens/block, 4 waves. Wave w owns token-tiles {w, 4+w} (A in regs, hoisted once),
// streams all 8 code-tiles per 128-code chunk from LDS (alternating 32KB buffers).
// LDS: R0 [0,32K) A-stage -> odd-chunk B -> ... ; R1 [32K,64K) even-chunk B -> cs gather;
//      cn[128] @64K, qsh[128] @64K+512.  Total 66560 B.
__launch_bounds__(256, 2)
__global__ void vq_screen_kernel(const float* __restrict__ x,
                                 const uint4* __restrict__ lutbf4,
                                 const float* __restrict__ lut,
                                 const float* __restrict__ norms,
                                 float* __restrict__ d_out,
                                 int* __restrict__ flaglist,
                                 int* __restrict__ flagcnt) {
    extern __shared__ char smc[];
    float* cn  = reinterpret_cast<float*>(smc + 65536);
    int*   qsh = reinterpret_cast<int*>(smc + 66048);

    const int tid = threadIdx.x;
    const int w = tid >> 6, lane = tid & 63;
    const int lcol = lane & 15, g = lane >> 4, g16 = g << 4;
    const int t0 = blockIdx.x * 128;
    const long xbase = (long)(t0 >> 12) * 262144 + (t0 & 4095);

    // ---- stage A (bf16-split, row-swizzled) into R0; writes analyze to 2-way (free) ----
#pragma unroll
    for (int i = 0; i < 8; ++i) {
        int item = tid + 256 * i;            // 0..2047
        int t = item & 127, q = item >> 7;   // token 0..127, d-quad 0..15
        const float* xp = x + xbase + (long)(4 * q) * 4096 + t;
        float v0 = xp[0], v1 = xp[4096], v2 = xp[8192], v3 = xp[12288];
        unsigned short h0 = rne_bf16(v0), h1 = rne_bf16(v1), h2 = rne_bf16(v2), h3 = rne_bf16(v3);
        unsigned short l0 = rne_bf16(v0 - bf16_to_f(h0)), l1 = rne_bf16(v1 - bf16_to_f(h1)),
                       l2 = rne_bf16(v2 - bf16_to_f(h2)), l3 = rne_bf16(v3 - bf16_to_f(h3));
        int rowb = t * 256, swz = (t & 7) << 4;
        *reinterpret_cast<u64*>(smc + rowb + ((q * 8) ^ swz)) = pack4(h0, h1, h2, h3);
        *reinterpret_cast<u64*>(smc + rowb + ((128 + q * 8) ^ swz)) = pack4(l0, l1, l2, l3);
    }

    // chunk-0 B into staging regs (overlaps A staging latency)
    uint4 streg[8];
#pragma unroll
    for (int i = 0; i < 8; ++i) streg[i] = lutbf4[(w * 8 + i) * 64 + lane];

    __syncthreads();                         // A visible

    // ---- hoist A fragments: 2 token-tiles x 6 k-steps = 48 VGPR, chunk-invariant ----
    constexpr int KA2[6] = {0, 64, 0, 64, 128, 192};   // xh,xh,xh,xh,xl,xl
    constexpr int KB2[6] = {0, 64, 128, 192, 0, 64};   // ch,ch,cl,cl,ch,ch
    const int swz16 = (lcol & 7) << 4;
    bf16x8 areg[2][6];
#pragma unroll
    for (int tt = 0; tt < 2; ++tt) {
        const char* arow = smc + ((tt * 4 + w) * 16 + lcol) * 256;
#pragma unroll
        for (int s = 0; s < 6; ++s)
            areg[tt][s] = *reinterpret_cast<const bf16x8*>(arow + ((KA2[s] + g16) ^ swz16));
    }

    float b1[2][4], b2[2][4]; int i1[2][4];
#pragma unroll
    for (int tt = 0; tt < 2; ++tt)
#pragma unroll
        for (int r = 0; r < 4; ++r) { b1[tt][r] = 3.4e38f; b2[tt][r] = 3.4e38f; i1[tt][r] = 0; }

#define UPD(tt, r, av, cnv, idv) do {                       \
        float v_ = fmaf(-2.f, (av), (cnv));                 \
        bool lt_ = v_ < b1[tt][r];                          \
        float lose_ = lt_ ? b1[tt][r] : v_;                 \
        b2[tt][r] = fminf(b2[tt][r], lose_);                \
        if (lt_) { b1[tt][r] = v_; i1[tt][r] = (idv); }     \
    } while (0)

    for (int ch = 0; ch < 8; ++ch) {
        char* buf = (ch & 1) ? smc : (smc + 32768);
        // write current chunk (linear b128 -> 2-way banks), load next into regs
#pragma unroll
        for (int i = 0; i < 8; ++i)
            *reinterpret_cast<uint4*>(buf + (w * 8 + i) * 1024 + lane * 16) = streg[i];
        if (tid < 128) cn[tid] = norms[ch * 128 + tid];
        if (ch < 7) {
#pragma unroll
            for (int i = 0; i < 8; ++i)
                streg[i] = lutbf4[(ch + 1) * 2048 + (w * 8 + i) * 64 + lane];
        }
        __syncthreads();                     // buf + cn visible

#pragma unroll
        for (int ct = 0; ct < 8; ct += 2) {
            float cn0 = cn[ct * 16 + lcol], cn1 = cn[ct * 16 + 16 + lcol];
            const char* brow0 = buf + (ct * 16 + lcol) * 256;
            const char* brow1 = brow0 + 4096;
            f32x4 a00 = {0.f,0.f,0.f,0.f}, a01 = {0.f,0.f,0.f,0.f};
            f32x4 a10 = {0.f,0.f,0.f,0.f}, a11 = {0.f,0.f,0.f,0.f};
#pragma unroll
            for (int s = 0; s < 6; ++s) {
                bf16x8 bb0 = *reinterpret_cast<const bf16x8*>(brow0 + ((KB2[s] + g16) ^ swz16));
                bf16x8 bb1 = *reinterpret_cast<const bf16x8*>(brow1 + ((KB2[s] + g16) ^ swz16));
                a00 = __builtin_amdgcn_mfma_f32_16x16x32_bf16(areg[0][s], bb0, a00, 0, 0, 0);
                a01 = __builtin_amdgcn_mfma_f32_16x16x32_bf16(areg[0][s], bb1, a01, 0, 0, 0);
                a10 = __builtin_amdgcn_mfma_f32_16x16x32_bf16(areg[1][s], bb0, a10, 0, 0, 0);
                a11 = __builtin_amdgcn_mfma_f32_16x16x32_bf16(areg[1][s], bb1, a11, 0, 0, 0);
            }
            int id0 = ch * 128 + ct * 16 + lcol, id1 = id0 + 16;
#pragma unroll
            for (int r = 0; r < 4; ++r) {
                UPD(0, r, a00[r], cn0, id0); UPD(0, r, a01[r], cn1, id1);
                UPD(1, r, a10[r], cn0, id0); UPD(1, r, a11[r], cn1, id1);
            }
        }
        __syncthreads();                     // cn/buf reads done before next overwrite
    }
#undef UPD

    // ---- merge 16 lanes (disjoint code subsets), id tie-break ----
#pragma unroll
    for (int m = 1; m <= 8; m <<= 1) {
#pragma unroll
        for (int tt = 0; tt < 2; ++tt)
#pragma unroll
            for (int r = 0; r < 4; ++r) {
                float ob1 = __shfl_xor(b1[tt][r], m, 64);
                int   oi1 = __shfl_xor(i1[tt][r], m, 64);
                float ob2 = __shfl_xor(b2[tt][r], m, 64);
                bool take = (ob1 < b1[tt][r]) || (ob1 == b1[tt][r] && oi1 < i1[tt][r]);
                float lose = take ? b1[tt][r] : ob1;
                b2[tt][r] = fminf(fminf(b2[tt][r], ob2), lose);
                if (take) { b1[tt][r] = ob1; i1[tt][r] = oi1; }
            }
    }
    if (lcol == 0) {
#pragma unroll
        for (int tt = 0; tt < 2; ++tt)
#pragma unroll
            for (int r = 0; r < 4; ++r) {
                int tl = (tt * 4 + w) * 16 + g * 4 + r;
                qsh[tl] = i1[tt][r];
                d_out[QX_OFF + t0 + tl] = (float)i1[tt][r];
                if (b2[tt][r] - b1[tt][r] <= MARGIN_D2) {
                    int slot = atomicAdd(flagcnt, 1);
                    flaglist[slot] = t0 + tl;
                }
            }
    }
    __syncthreads();

    // ---- fused epilogue: gather codes -> cs[d][128] in R1, write out = 2x - c, loss ----
    float* cs = reinterpret_cast<float*>(smc + 32768);
    {
        int t = tid >> 1, half = tid & 1;
        int q = qsh[t];
        const float4* src = reinterpret_cast<const float4*>(lut + q * 64 + half * 32);
#pragma unroll
        for (int k = 0; k < 8; ++k) {
            float4 v = src[k];
            int dbase = half * 32 + k * 4;
            cs[(dbase + 0) * 128 + t] = v.x;
            cs[(dbase + 1) * 128 + t] = v.y;
            cs[(dbase + 2) * 128 + t] = v.z;
            cs[(dbase + 3) * 128 + t] = v.w;
        }
    }
    __syncthreads();

    float lsum = 0.f;
    {
        int t4 = (tid & 31) * 4, db = tid >> 5;
#pragma unroll
        for (int it = 0; it < 8; ++it) {
            int d = it * 8 + db;
            float4 xv = *reinterpret_cast<const float4*>(x + xbase + (long)d * 4096 + t4);
            float4 cv = *reinterpret_cast<const float4*>(cs + d * 128 + t4);
            float4 ov;
            ov.x = 2.f * xv.x - cv.x; ov.y = 2.f * xv.y - cv.y;
            ov.z = 2.f * xv.z - cv.z; ov.w = 2.f * xv.w - cv.w;
            *reinterpret_cast<float4*>(d_out + xbase + (long)d * 4096 + t4) = ov;
            float e0 = xv.x - cv.x, e1 = xv.y - cv.y, e2 = xv.z - cv.z, e3 = xv.w - cv.w;
            lsum += e0 * e0 + e1 * e1 + e2 * e2 + e3 * e3;
        }
    }
#pragma unroll
    for (int off = 32; off >= 1; off >>= 1)
        lsum += __shfl_down(lsum, off, 64);
    if ((tid & 63) == 0)
        atomicAdd(&d_out[LOSS_OFF], lsum * (1.25f / 8388608.f));
}

// ---------------- rescan: 16 flagged tokens / block-iteration; verbatim exact arithmetic ----
// Fixes q_x, out (64 floats), and loss delta for corrected tokens.
__launch_bounds__(256, 2)
__global__ void vq_rescan_kernel(const float* __restrict__ x,
                                 const float* __restrict__ lut,
                                 const float* __restrict__ norms,
                                 float* __restrict__ d_out,
                                 const int* __restrict__ flaglist,
                                 const int* __restrict__ flagcnt) {
    __shared__ float sx[16][64];
    __shared__ int   tlist[16];
    __shared__ float wbv[16][4];
    __shared__ int   wbj[16][4];
    __shared__ int   oldq[16], newq[16];
    const int tid = threadIdx.x, w = tid >> 6, lane = tid & 63;
    const int cnt = *flagcnt;

    for (int base = blockIdx.x * 16; base < cnt; base += gridDim.x * 16) {
        int n = cnt - base; if (n > 16) n = 16;
        __syncthreads();                     // protect sx/tlist reuse across iterations
        if (tid < 16) tlist[tid] = flaglist[base + (tid < n ? tid : 0)];
        __syncthreads();
#pragma unroll
        for (int i = 0; i < 4; ++i) {
            int item = tid + 256 * i;
            int s = item >> 6, d = item & 63;
            int tk = tlist[s];
            sx[s][d] = x[(long)(tk >> 12) * 262144 + (tk & 4095) + (long)d * 4096];
        }
        __syncthreads();

        float bv[16]; int bj[16];
#pragma unroll
        for (int s = 0; s < 16; ++s) { bv[s] = 3.4e38f; bj[s] = 0; }

        for (int j0 = 0; j0 < 4; ++j0) {
            int j = tid * 4 + j0;            // ascending per thread -> first-min tie-break
            const float4* cf4 = reinterpret_cast<const float4*>(lut + j * 64);
            float4 creg[16];
#pragma unroll
            for (int q = 0; q < 16; ++q) creg[q] = cf4[q];
            float nj = norms[j];
#pragma unroll
            for (int s = 0; s < 16; ++s) {
                const float4* xf4 = reinterpret_cast<const float4*>(&sx[s][0]);
                float acc = 0.f;
#pragma unroll
                for (int q = 0; q < 16; ++q) {
                    float4 xf = xf4[q], cf = creg[q];
                    acc += xf.x * cf.x + xf.y * cf.y + xf.z * cf.z + xf.w * cf.w;  // verbatim
                }
                float v = nj - 2.f * acc;    // verbatim
                if (v < bv[s]) { bv[s] = v; bj[s] = j; }
            }
        }
        // wave merge (64 threads cover 256 codes), id tie-break
#pragma unroll
        for (int m = 1; m <= 32; m <<= 1) {
#pragma unroll
            for (int s = 0; s < 16; ++s) {
                float ov = __shfl_xor(bv[s], m, 64);
                int   oj = __shfl_xor(bj[s], m, 64);
                if (ov < bv[s] || (ov == bv[s] && oj < bj[s])) { bv[s] = ov; bj[s] = oj; }
            }
        }
        if (lane == 0) {
#pragma unroll
            for (int s = 0; s < 16; ++s) { wbv[s][w] = bv[s]; wbj[s][w] = bj[s]; }
        }
        __syncthreads();
        if (tid < 16) {
            float fv = wbv[tid][0]; int fj = wbj[tid][0];
#pragma unroll
            for (int ww = 1; ww < 4; ++ww) {
                float ov = wbv[tid][ww]; int oj = wbj[tid][ww];
                if (ov < fv || (ov == fv && oj < fj)) { fv = ov; fj = oj; }
            }
            int tk = tlist[tid];
            int old = (int)d_out[QX_OFF + tk];
            oldq[tid] = old;
            int nq = (tid < n && fj != old) ? fj : -1;
            newq[tid] = nq;
            if (nq >= 0) d_out[QX_OFF + tk] = (float)nq;
        }
        __syncthreads();
        // corrections: wave w handles slots w, w+4, w+8, w+12
#pragma unroll
        for (int k = 0; k < 4; ++k) {
            int s = w + k * 4;
            int nq = newq[s];
            if (nq >= 0) {
                int tk = tlist[s];
                long xb = (long)(tk >> 12) * 262144 + (tk & 4095);
                float xv = sx[s][lane];
                float cnw = lut[nq * 64 + lane];
                float cow = lut[oldq[s] * 64 + lane];
                d_out[xb + (long)lane * 4096] = 2.f * xv - cnw;
                float dl = (xv - cnw) * (xv - cnw) - (xv - cow) * (xv - cow);
#pragma unroll
                for (int off = 32; off >= 1; off >>= 1)
                    dl += __shfl_down(dl, off, 64);
                if (lane == 0)
                    atomicAdd(&d_out[LOSS_OFF], dl * (1.25f / 8388608.f));
            }
        }
    }
}

extern "C" void kernel_launch(void* const* d_in, const int* in_sizes, int n_in,
                              void* d_out, int out_size, void* d_ws, size_t ws_size,
                              hipStream_t stream) {
    const float* x   = (const float*)d_in[0];   // [32,64,64,64] f32
    const float* lut = (const float*)d_in[1];   // [1024,64] f32
    float* out = (float*)d_out;
    char* ws = (char*)d_ws;
    float* norms    = (float*)ws;                        // 4 KB
    char*  lutbfB   = ws + 4096;                         // 256 KB pre-swizzled bf16-split
    int*   flagcnt  = (int*)(ws + 266240);
    int*   flaglist = (int*)(ws + 266256);               // worst case 512 KB

    vq_prep_kernel<<<4, 256, 0, stream>>>(lut, norms, lutbfB, flagcnt, out);
    vq_screen_kernel<<<1024, 256, 66560, stream>>>(x, (const uint4*)lutbfB, lut, norms,
                                                   out, flaglist, flagcnt);
    vq_rescan_kernel<<<512, 256, 0, stream>>>(x, lut, norms, out, flaglist, flagcnt);
}

// Round 7
// 272.682 us; speedup vs baseline: 1.9243x; 1.5506x over previous
//
#include <hip/hip_runtime.h>

#define QX_OFF    8388608
#define LOSS_OFF  8519680
#define MARGIN_V  0.02f      // on v=(d2-||x||^2)/2 scale => 0.04 on d2; analytic need ~0.009

typedef __attribute__((ext_vector_type(8))) short bf16x8;
typedef __attribute__((ext_vector_type(4))) float f32x4;
typedef unsigned long long u64;
typedef unsigned int u32;

static __device__ __forceinline__ unsigned short rne_bf16(float f) {
    unsigned u = __float_as_uint(f);
    u += 0x7FFFu + ((u >> 16) & 1u);
    return (unsigned short)(u >> 16);
}
static __device__ __forceinline__ float bf16_to_f(unsigned short h) {
    return __uint_as_float(((unsigned)h) << 16);
}
static __device__ __forceinline__ u64 pack4(unsigned short a, unsigned short b,
                                            unsigned short c, unsigned short d) {
    return (u64)a | ((u64)b << 16) | ((u64)c << 32) | ((u64)d << 48);
}

// ---------------- prep: exact norms (verbatim round-1 expr) + plain bf16-split codebook ----
// lutbfB row c (256 B): bytes 0..127 = high bf16 (dims 4i at byte 8i), 128..255 = low bf16.
__global__ void vq_prep_kernel(const float* __restrict__ lut,
                               float* __restrict__ norms,
                               char* __restrict__ lutbfB,
                               int* __restrict__ flagcnt,
                               float* __restrict__ d_out) {
    int c = blockIdx.x * 256 + threadIdx.x;
    if (c == 0) { d_out[LOSS_OFF] = 0.f; *flagcnt = 0; }
    if (c < 1024) {
        const float4* c4 = reinterpret_cast<const float4*>(lut + c * 64);
        float s = 0.f;
        u64 hq[16], lq[16];
#pragma unroll
        for (int i = 0; i < 16; ++i) {
            float4 v = c4[i];
            s += v.x * v.x + v.y * v.y + v.z * v.z + v.w * v.w;   // verbatim (exact path)
            unsigned short h0 = rne_bf16(v.x), h1 = rne_bf16(v.y),
                           h2 = rne_bf16(v.z), h3 = rne_bf16(v.w);
            unsigned short l0 = rne_bf16(v.x - bf16_to_f(h0)), l1 = rne_bf16(v.y - bf16_to_f(h1)),
                           l2 = rne_bf16(v.z - bf16_to_f(h2)), l3 = rne_bf16(v.w - bf16_to_f(h3));
            hq[i] = pack4(h0, h1, h2, h3);
            lq[i] = pack4(l0, l1, l2, l3);
        }
        norms[c] = s;
        u64* dst = reinterpret_cast<u64*>(lutbfB + c * 256);
#pragma unroll
        for (int i = 0; i < 16; ++i) { dst[i] = hq[i]; dst[16 + i] = lq[i]; }
    }
}

// ---------------- screen: B-in-registers, token-streaming, packed argmin ----------------
// 256 blocks x 512 thr (8 waves). Wave w owns codes [w*128, w*128+128) as 32 bf16x8 regs.
// Tokens: 512/block, streamed as 16 pairs of 16-token tiles through a 2-pair LDS dbuf.
// A-tile row = 272 B padded (bank-balanced b128 reads/writes, no XOR).
// LDS: A dbuf 2*8704 = 17408 | scoreboard 512 tok x 17 u32 = 34816  => 52224 B.
__launch_bounds__(512, 2)
__global__ void vq_screen_kernel(const float* __restrict__ x,
                                 const char* __restrict__ lutbfB,
                                 const float* __restrict__ norms,
                                 float* __restrict__ d_out,
                                 int* __restrict__ flaglist,
                                 int* __restrict__ flagcnt) {
    extern __shared__ char smc[];
    u32* sb = reinterpret_cast<u32*>(smc + 17408);

    const int tid  = threadIdx.x;
    const int w    = tid >> 6, lane = tid & 63;
    const int lcol = lane & 15, g = lane >> 4, g16 = g << 4;
    const int t0   = blockIdx.x * 512;
    const long xbase = (long)(t0 >> 12) * 262144 + (t0 & 4095);

    // ---- prologue: wave-private B fragments + C-init (128 + ||c||^2/2), one-time ----
    bf16x8 breg[8][4];
    float  cni[8];
#pragma unroll
    for (int ctl = 0; ctl < 8; ++ctl) {
        int c = (w * 8 + ctl) * 16 + lcol;
        const char* row = lutbfB + c * 256;
#pragma unroll
        for (int kb = 0; kb < 4; ++kb)
            breg[ctl][kb] = *reinterpret_cast<const bf16x8*>(row + kb * 64 + g16);
        cni[ctl] = 128.f + 0.5f * norms[c];
    }

    // staging identity: thread = (tl = tid>>8, qg = (tid>>4)&15, tok = tid&15)
    const int tok = tid & 15, qg = (tid >> 4) & 15, tl = tid >> 8;
    float xr[4];

#define LOADP(p) do {                                                          \
        const float* xp = x + xbase + (long)(4 * qg) * 4096                    \
                          + ((p) * 32 + tl * 16 + tok);                        \
        xr[0] = xp[0]; xr[1] = xp[4096]; xr[2] = xp[8192]; xr[3] = xp[12288];  \
    } while (0)

#define WRITEP(bufsel) do {                                                    \
        char* row = smc + (bufsel) * 8704 + tl * 4352 + tok * 272;             \
        unsigned short h0 = rne_bf16(xr[0]), h1 = rne_bf16(xr[1]),             \
                       h2 = rne_bf16(xr[2]), h3 = rne_bf16(xr[3]);             \
        unsigned short l0 = rne_bf16(xr[0] - bf16_to_f(h0)),                   \
                       l1 = rne_bf16(xr[1] - bf16_to_f(h1)),                   \
                       l2 = rne_bf16(xr[2] - bf16_to_f(h2)),                   \
                       l3 = rne_bf16(xr[3] - bf16_to_f(h3));                   \
        *reinterpret_cast<u64*>(row + qg * 8) =                                \
            pack4(h0, h1, h2, h3) ^ 0x8000800080008000ULL;                     \
        *reinterpret_cast<u64*>(row + 128 + qg * 8) =                          \
            pack4(l0, l1, l2, l3) ^ 0x8000800080008000ULL;                     \
    } while (0)

    LOADP(0); WRITEP(0); LOADP(1);

    const u32 VMASK = 0xFFFFFF80u;

    for (int tp = 0; tp < 16; ++tp) {
        if (tp < 15) WRITEP((tp + 1) & 1);     // pair tp+1 from regs
        if (tp < 14) LOADP(tp + 2);            // issue pair tp+2 loads
        __syncthreads();                       // A-pair tp visible
        const char* pbase = smc + (tp & 1) * 8704;

#pragma unroll
        for (int tl2 = 0; tl2 < 2; ++tl2) {
            const char* arow = pbase + tl2 * 4352 + lcol * 272;
            bf16x8 a0 = *reinterpret_cast<const bf16x8*>(arow + g16);        // xh dims 0-31
            bf16x8 a1 = *reinterpret_cast<const bf16x8*>(arow + 64 + g16);   // xh 32-63
            bf16x8 a2 = *reinterpret_cast<const bf16x8*>(arow + 128 + g16);  // xl 0-31
            bf16x8 a3 = *reinterpret_cast<const bf16x8*>(arow + 192 + g16);  // xl 32-63

            f32x4 acc[8];
#pragma unroll
            for (int ctl = 0; ctl < 8; ++ctl) {
                float v = cni[ctl];
                acc[ctl] = (f32x4){v, v, v, v};
            }
#pragma unroll
            for (int ctl = 0; ctl < 8; ++ctl)
                acc[ctl] = __builtin_amdgcn_mfma_f32_16x16x32_bf16(a0, breg[ctl][0], acc[ctl], 0, 0, 0);
#pragma unroll
            for (int ctl = 0; ctl < 8; ++ctl)
                acc[ctl] = __builtin_amdgcn_mfma_f32_16x16x32_bf16(a1, breg[ctl][1], acc[ctl], 0, 0, 0);
#pragma unroll
            for (int ctl = 0; ctl < 8; ++ctl)
                acc[ctl] = __builtin_amdgcn_mfma_f32_16x16x32_bf16(a0, breg[ctl][2], acc[ctl], 0, 0, 0);
#pragma unroll
            for (int ctl = 0; ctl < 8; ++ctl)
                acc[ctl] = __builtin_amdgcn_mfma_f32_16x16x32_bf16(a1, breg[ctl][3], acc[ctl], 0, 0, 0);
#pragma unroll
            for (int ctl = 0; ctl < 8; ++ctl)
                acc[ctl] = __builtin_amdgcn_mfma_f32_16x16x32_bf16(a2, breg[ctl][0], acc[ctl], 0, 0, 0);
#pragma unroll
            for (int ctl = 0; ctl < 8; ++ctl)
                acc[ctl] = __builtin_amdgcn_mfma_f32_16x16x32_bf16(a3, breg[ctl][1], acc[ctl], 0, 0, 0);

            // packed 2-min argmin: u = trunc7(v) | (ctl<<4|lcol); umin order == (v, id) order
            u32 m1[4] = {0xFFFFFFFFu, 0xFFFFFFFFu, 0xFFFFFFFFu, 0xFFFFFFFFu};
            u32 m2[4] = {0xFFFFFFFFu, 0xFFFFFFFFu, 0xFFFFFFFFu, 0xFFFFFFFFu};
#pragma unroll
            for (int ctl = 0; ctl < 8; ++ctl) {
                u32 tag = (u32)((ctl << 4) | lcol);
#pragma unroll
                for (int r = 0; r < 4; ++r) {
                    u32 u = (__float_as_uint(acc[ctl][r]) & VMASK) | tag;
                    m2[r] = min(m2[r], max(m1[r], u));
                    m1[r] = min(m1[r], u);
                }
            }
            // merge the 16 lcol lanes (disjoint codes; id embedded -> pure umin)
#pragma unroll
            for (int m = 1; m <= 8; m <<= 1) {
#pragma unroll
                for (int r = 0; r < 4; ++r) {
                    u32 o1 = (u32)__shfl_xor((int)m1[r], m, 64);
                    u32 o2 = (u32)__shfl_xor((int)m2[r], m, 64);
                    m2[r] = min(min(m2[r], o2), max(m1[r], o1));
                    m1[r] = min(m1[r], o1);
                }
            }
            if (lcol == 0) {
#pragma unroll
                for (int r = 0; r < 4; ++r) {
                    int t = tp * 32 + tl2 * 16 + g * 4 + r;
                    sb[t * 17 + w * 2]     = m1[r];
                    sb[t * 17 + w * 2 + 1] = m2[r];
                }
            }
        }
        __syncthreads();                       // reads done before pair overwrite
    }
#undef LOADP
#undef WRITEP

    // ---- final merge: thread t = one token, 8 wave strips (w ascending keeps lowest id) ----
    {
        int t = tid;
        u32 b1 = sb[t * 17], b2 = sb[t * 17 + 1];
        int bw = 0;
#pragma unroll
        for (int ww = 1; ww < 8; ++ww) {
            u32 c1 = sb[t * 17 + ww * 2], c2 = sb[t * 17 + ww * 2 + 1];
            b2 = min(min(b2, c2), max(b1, c1));
            if (c1 < b1) { b1 = c1; bw = ww; }
        }
        int id = bw * 128 + (int)(b1 & 127u);
        d_out[QX_OFF + t0 + t] = (float)id;
        float gap = __uint_as_float(b2 & VMASK) - __uint_as_float(b1 & VMASK);
        if (gap <= MARGIN_V) {
            int slot = atomicAdd(flagcnt, 1);
            flaglist[slot] = t0 + t;
        }
    }
}

// ---------------- rescan: wave-per-token, exact fp32 (verbatim round-1 association) ----
// Lane handles 16 codes (j = lane + 64k); x broadcast from LDS hoisted over k; acc[16] only.
__global__ void vq_rescan_kernel(const float* __restrict__ x,
                                 const float* __restrict__ lut,
                                 const float* __restrict__ norms,
                                 float* __restrict__ d_out,
                                 const int* __restrict__ flaglist,
                                 const int* __restrict__ flagcnt) {
    __shared__ float xsh[4 * 68];
    const int tid = threadIdx.x, w = tid >> 6, lane = tid & 63;
    const int cnt = *flagcnt;
    const float4* lut4 = reinterpret_cast<const float4*>(lut);

    for (int idx = blockIdx.x * 4 + w; idx < cnt; idx += 2048 * 4) {
        int tk = flaglist[idx];
        xsh[w * 68 + lane] = x[(long)(tk >> 12) * 262144 + (tk & 4095) + (long)lane * 4096];
        const float4* xf4 = reinterpret_cast<const float4*>(xsh + w * 68);

        float acc[16];
#pragma unroll
        for (int k = 0; k < 16; ++k) acc[k] = 0.f;

        for (int q = 0; q < 16; ++q) {
            float4 xf = xf4[q];                              // wave-broadcast
#pragma unroll
            for (int k = 0; k < 16; ++k) {
                float4 cf = lut4[(lane + 64 * k) * 16 + q];  // L2-hot gather
                acc[k] += xf.x * cf.x + xf.y * cf.y + xf.z * cf.z + xf.w * cf.w;  // verbatim
            }
        }
        float bv = 3.4e38f; int bj = 0;
#pragma unroll
        for (int k = 0; k < 16; ++k) {
            int j = lane + 64 * k;                           // ascending per lane
            float v = norms[j] - 2.f * acc[k];               // verbatim
            if (v < bv) { bv = v; bj = j; }
        }
#pragma unroll
        for (int m = 1; m <= 32; m <<= 1) {
            float ov = __shfl_xor(bv, m, 64);
            int   oj = __shfl_xor(bj, m, 64);
            if (ov < bv || (ov == bv && oj < bj)) { bv = ov; bj = oj; }
        }
        if (lane == 0) d_out[QX_OFF + tk] = (float)bj;
    }
}

// ---------------- epilogue: out = 2x - x_e (float4), loss — verbatim proven version ----
__global__ void vq_epilogue_kernel(const float* __restrict__ x,
                                   const float* __restrict__ lut,
                                   float* __restrict__ d_out) {
    __shared__ float cs[8192];                     // [d][128 tokens]
    __shared__ int qsh[128];
    const int tid = threadIdx.x;
    const int t0 = blockIdx.x * 128;
    const long xbase = (long)(t0 >> 12) * 262144 + (t0 & 4095);

    if (tid < 128) qsh[tid] = (int)d_out[QX_OFF + t0 + tid];
    __syncthreads();
    {
        int t = tid >> 1, half = tid & 1;
        int q = qsh[t];
        const float4* src = reinterpret_cast<const float4*>(lut + q * 64 + half * 32);
#pragma unroll
        for (int k = 0; k < 8; ++k) {
            float4 v = src[k];
            int dbase = half * 32 + k * 4;
            cs[(dbase + 0) * 128 + t] = v.x;
            cs[(dbase + 1) * 128 + t] = v.y;
            cs[(dbase + 2) * 128 + t] = v.z;
            cs[(dbase + 3) * 128 + t] = v.w;
        }
    }
    __syncthreads();

    float lsum = 0.f;
    {
        int t4 = (tid & 31) * 4, db = tid >> 5;
#pragma unroll
        for (int it = 0; it < 8; ++it) {
            int d = it * 8 + db;
            float4 xv = *reinterpret_cast<const float4*>(x + xbase + (long)d * 4096 + t4);
            float4 cv = *reinterpret_cast<const float4*>(cs + d * 128 + t4);
            float4 ov;
            ov.x = 2.f * xv.x - cv.x; ov.y = 2.f * xv.y - cv.y;
            ov.z = 2.f * xv.z - cv.z; ov.w = 2.f * xv.w - cv.w;
            *reinterpret_cast<float4*>(d_out + xbase + (long)d * 4096 + t4) = ov;
            float e0 = xv.x - cv.x, e1 = xv.y - cv.y, e2 = xv.z - cv.z, e3 = xv.w - cv.w;
            lsum += e0 * e0 + e1 * e1 + e2 * e2 + e3 * e3;
        }
    }
#pragma unroll
    for (int off = 32; off >= 1; off >>= 1)
        lsum += __shfl_down(lsum, off, 64);
    if ((tid & 63) == 0)
        atomicAdd(&d_out[LOSS_OFF], lsum * (1.25f / 8388608.f));
}

extern "C" void kernel_launch(void* const* d_in, const int* in_sizes, int n_in,
                              void* d_out, int out_size, void* d_ws, size_t ws_size,
                              hipStream_t stream) {
    const float* x   = (const float*)d_in[0];   // [32,64,64,64] f32
    const float* lut = (const float*)d_in[1];   // [1024,64] f32
    float* out = (float*)d_out;
    char* ws = (char*)d_ws;
    float* norms    = (float*)ws;                        // 4 KB
    char*  lutbfB   = ws + 4096;                         // 256 KB bf16-split codebook
    int*   flagcnt  = (int*)(ws + 266240);
    int*   flaglist = (int*)(ws + 266256);               // worst case 512 KB

    vq_prep_kernel<<<4, 256, 0, stream>>>(lut, norms, lutbfB, flagcnt, out);
    vq_screen_kernel<<<256, 512, 52224, stream>>>(x, lutbfB, norms, out, flaglist, flagcnt);
    vq_rescan_kernel<<<2048, 256, 0, stream>>>(x, lut, norms, out, flaglist, flagcnt);
    vq_epilogue_kernel<<<1024, 256, 0, stream>>>(x, lut, out);
}

// Round 8
// 232.288 us; speedup vs baseline: 2.2590x; 1.1739x over previous
//
#include <hip/hip_runtime.h>

#define QX_OFF    8388608
#define LOSS_OFF  8519680
#define MARGIN_V  0.02f      // on v=(d2-||x||^2)/2 scale => 0.04 on d2; analytic need ~0.009

typedef __attribute__((ext_vector_type(8))) short bf16x8;
typedef __attribute__((ext_vector_type(4))) float f32x4;
typedef unsigned long long u64;
typedef unsigned int u32;

static __device__ __forceinline__ unsigned short rne_bf16(float f) {
    unsigned u = __float_as_uint(f);
    u += 0x7FFFu + ((u >> 16) & 1u);
    return (unsigned short)(u >> 16);
}
static __device__ __forceinline__ float bf16_to_f(unsigned short h) {
    return __uint_as_float(((unsigned)h) << 16);
}
static __device__ __forceinline__ u64 pack4(unsigned short a, unsigned short b,
                                            unsigned short c, unsigned short d) {
    return (u64)a | ((u64)b << 16) | ((u64)c << 32) | ((u64)d << 48);
}

// ---------------- prep: exact norms (verbatim round-1 expr) + plain bf16-split codebook ----
// lutbfB row c (256 B): bytes 0..127 = high bf16 (dim 4i at byte 8i), 128..255 = low bf16.
__global__ void vq_prep_kernel(const float* __restrict__ lut,
                               float* __restrict__ norms,
                               char* __restrict__ lutbfB,
                               int* __restrict__ flagcnt) {
    int c = blockIdx.x * 256 + threadIdx.x;
    if (c == 0) *flagcnt = 0;
    if (c < 1024) {
        const float4* c4 = reinterpret_cast<const float4*>(lut + c * 64);
        float s = 0.f;
        u64 hq[16], lq[16];
#pragma unroll
        for (int i = 0; i < 16; ++i) {
            float4 v = c4[i];
            s += v.x * v.x + v.y * v.y + v.z * v.z + v.w * v.w;   // verbatim (exact path)
            unsigned short h0 = rne_bf16(v.x), h1 = rne_bf16(v.y),
                           h2 = rne_bf16(v.z), h3 = rne_bf16(v.w);
            unsigned short l0 = rne_bf16(v.x - bf16_to_f(h0)), l1 = rne_bf16(v.y - bf16_to_f(h1)),
                           l2 = rne_bf16(v.z - bf16_to_f(h2)), l3 = rne_bf16(v.w - bf16_to_f(h3));
            hq[i] = pack4(h0, h1, h2, h3);
            lq[i] = pack4(l0, l1, l2, l3);
        }
        norms[c] = s;
        u64* dst = reinterpret_cast<u64*>(lutbfB + c * 256);
#pragma unroll
        for (int i = 0; i < 16; ++i) { dst[i] = hq[i]; dst[16 + i] = lq[i]; }
    }
}

// ---------------- screen: B-in-registers, token-streaming, packed argmin ----------------
// 512 blocks x 512 thr (8 waves) = 2 blocks/CU. Wave w owns codes [w*128,(w+1)*128) in regs.
// 256 tokens/block streamed as 8 pairs of 2x16-token tiles through a 2-pair LDS dbuf.
// LDS: A dbuf 2*8704 = 17408 | scoreboard 256 tok x 17 u32 = 17408  => 34816 B.
__launch_bounds__(512, 2)
__global__ void vq_screen_kernel(const float* __restrict__ x,
                                 const char* __restrict__ lutbfB,
                                 const float* __restrict__ norms,
                                 float* __restrict__ d_out,
                                 int* __restrict__ flaglist,
                                 int* __restrict__ flagcnt) {
    extern __shared__ char smc[];
    u32* sb = reinterpret_cast<u32*>(smc + 17408);

    const int tid  = threadIdx.x;
    const int w    = tid >> 6, lane = tid & 63;
    const int lcol = lane & 15, g = lane >> 4, g16 = g << 4;
    const int t0   = blockIdx.x * 256;
    const long xbase = (long)(t0 >> 12) * 262144 + (t0 & 4095);

    // ---- prologue: wave-private B fragments + C-init (128 + ||c||^2/2), one-time ----
    bf16x8 breg[8][4];
    float  cni[8];
#pragma unroll
    for (int ctl = 0; ctl < 8; ++ctl) {
        int c = (w * 8 + ctl) * 16 + lcol;
        const char* row = lutbfB + c * 256;
#pragma unroll
        for (int kb = 0; kb < 4; ++kb)
            breg[ctl][kb] = *reinterpret_cast<const bf16x8*>(row + kb * 64 + g16);
        cni[ctl] = 128.f + 0.5f * norms[c];
    }

    // staging identity: thread = (tl = tid>>8, qg = (tid>>4)&15, tok = tid&15)
    const int tok = tid & 15, qg = (tid >> 4) & 15, tl = tid >> 8;
    float xr[4];

#define LOADP(p) do {                                                          \
        const float* xp = x + xbase + (long)(4 * qg) * 4096                    \
                          + ((p) * 32 + tl * 16 + tok);                        \
        xr[0] = xp[0]; xr[1] = xp[4096]; xr[2] = xp[8192]; xr[3] = xp[12288];  \
    } while (0)

#define WRITEP(bufsel) do {                                                    \
        char* row = smc + (bufsel) * 8704 + tl * 4352 + tok * 272;             \
        unsigned short h0 = rne_bf16(xr[0]), h1 = rne_bf16(xr[1]),             \
                       h2 = rne_bf16(xr[2]), h3 = rne_bf16(xr[3]);             \
        unsigned short l0 = rne_bf16(xr[0] - bf16_to_f(h0)),                   \
                       l1 = rne_bf16(xr[1] - bf16_to_f(h1)),                   \
                       l2 = rne_bf16(xr[2] - bf16_to_f(h2)),                   \
                       l3 = rne_bf16(xr[3] - bf16_to_f(h3));                   \
        *reinterpret_cast<u64*>(row + qg * 8) =                                \
            pack4(h0, h1, h2, h3) ^ 0x8000800080008000ULL;                     \
        *reinterpret_cast<u64*>(row + 128 + qg * 8) =                          \
            pack4(l0, l1, l2, l3) ^ 0x8000800080008000ULL;                     \
    } while (0)

    LOADP(0); WRITEP(0); LOADP(1);

    const u32 VMASK = 0xFFFFFF80u;

    for (int tp = 0; tp < 8; ++tp) {
        if (tp < 7) WRITEP((tp + 1) & 1);      // pair tp+1 from regs
        if (tp < 6) LOADP(tp + 2);             // issue pair tp+2 loads
        __syncthreads();                       // A-pair tp visible
        const char* pbase = smc + (tp & 1) * 8704;

#pragma unroll
        for (int tl2 = 0; tl2 < 2; ++tl2) {
            const char* arow = pbase + tl2 * 4352 + lcol * 272;
            bf16x8 a0 = *reinterpret_cast<const bf16x8*>(arow + g16);        // xh dims 0-31
            bf16x8 a1 = *reinterpret_cast<const bf16x8*>(arow + 64 + g16);   // xh 32-63
            bf16x8 a2 = *reinterpret_cast<const bf16x8*>(arow + 128 + g16);  // xl 0-31
            bf16x8 a3 = *reinterpret_cast<const bf16x8*>(arow + 192 + g16);  // xl 32-63

            f32x4 acc[8];
#pragma unroll
            for (int ctl = 0; ctl < 8; ++ctl) {
                float v = cni[ctl];
                acc[ctl] = (f32x4){v, v, v, v};
            }
#pragma unroll
            for (int ctl = 0; ctl < 8; ++ctl)
                acc[ctl] = __builtin_amdgcn_mfma_f32_16x16x32_bf16(a0, breg[ctl][0], acc[ctl], 0, 0, 0);
#pragma unroll
            for (int ctl = 0; ctl < 8; ++ctl)
                acc[ctl] = __builtin_amdgcn_mfma_f32_16x16x32_bf16(a1, breg[ctl][1], acc[ctl], 0, 0, 0);
#pragma unroll
            for (int ctl = 0; ctl < 8; ++ctl)
                acc[ctl] = __builtin_amdgcn_mfma_f32_16x16x32_bf16(a0, breg[ctl][2], acc[ctl], 0, 0, 0);
#pragma unroll
            for (int ctl = 0; ctl < 8; ++ctl)
                acc[ctl] = __builtin_amdgcn_mfma_f32_16x16x32_bf16(a1, breg[ctl][3], acc[ctl], 0, 0, 0);
#pragma unroll
            for (int ctl = 0; ctl < 8; ++ctl)
                acc[ctl] = __builtin_amdgcn_mfma_f32_16x16x32_bf16(a2, breg[ctl][0], acc[ctl], 0, 0, 0);
#pragma unroll
            for (int ctl = 0; ctl < 8; ++ctl)
                acc[ctl] = __builtin_amdgcn_mfma_f32_16x16x32_bf16(a3, breg[ctl][1], acc[ctl], 0, 0, 0);

            // packed 2-min argmin: u = trunc7(v) | (ctl<<4|lcol); umin order == (v, id) order
            u32 m1[4] = {0xFFFFFFFFu, 0xFFFFFFFFu, 0xFFFFFFFFu, 0xFFFFFFFFu};
            u32 m2[4] = {0xFFFFFFFFu, 0xFFFFFFFFu, 0xFFFFFFFFu, 0xFFFFFFFFu};
#pragma unroll
            for (int ctl = 0; ctl < 8; ++ctl) {
                u32 tag = (u32)((ctl << 4) | lcol);
#pragma unroll
                for (int r = 0; r < 4; ++r) {
                    u32 u = (__float_as_uint(acc[ctl][r]) & VMASK) | tag;
                    m2[r] = min(m2[r], max(m1[r], u));
                    m1[r] = min(m1[r], u);
                }
            }
            // merge the 16 lcol lanes (disjoint codes; id embedded -> pure umin)
#pragma unroll
            for (int m = 1; m <= 8; m <<= 1) {
#pragma unroll
                for (int r = 0; r < 4; ++r) {
                    u32 o1 = (u32)__shfl_xor((int)m1[r], m, 64);
                    u32 o2 = (u32)__shfl_xor((int)m2[r], m, 64);
                    m2[r] = min(min(m2[r], o2), max(m1[r], o1));
                    m1[r] = min(m1[r], o1);
                }
            }
            if (lcol == 0) {
#pragma unroll
                for (int r = 0; r < 4; ++r) {
                    int t = tp * 32 + tl2 * 16 + g * 4 + r;
                    sb[t * 17 + w * 2]     = m1[r];
                    sb[t * 17 + w * 2 + 1] = m2[r];
                }
            }
        }
        __syncthreads();                       // reads done before pair overwrite
    }
#undef LOADP
#undef WRITEP

    // ---- final merge: thread t = one token (256); per-wave batched flag append ----
    if (tid < 256) {
        int t = tid;
        u32 b1 = sb[t * 17], b2 = sb[t * 17 + 1];
        int bw = 0;
#pragma unroll
        for (int ww = 1; ww < 8; ++ww) {
            u32 c1 = sb[t * 17 + ww * 2], c2 = sb[t * 17 + ww * 2 + 1];
            b2 = min(min(b2, c2), max(b1, c1));
            if (c1 < b1) { b1 = c1; bw = ww; }
        }
        int id = bw * 128 + (int)(b1 & 127u);
        d_out[QX_OFF + t0 + t] = (float)id;
        float gap = __uint_as_float(b2 & VMASK) - __uint_as_float(b1 & VMASK);
        bool flag = (gap <= MARGIN_V);
        u64 mask = __ballot(flag);
        if (mask) {
            int base = 0;
            if (lane == 0) base = atomicAdd(flagcnt, __popcll(mask));
            base = __shfl(base, 0, 64);
            if (flag) {
                int off = __popcll(mask & ((1ULL << lane) - 1ULL));
                flaglist[base + off] = t0 + t;
            }
        }
    }
}

// ---------------- rescan: wave-per-token, exact fp32 (verbatim round-1 association) ----
__global__ void vq_rescan_kernel(const float* __restrict__ x,
                                 const float* __restrict__ lut,
                                 const float* __restrict__ norms,
                                 float* __restrict__ d_out,
                                 const int* __restrict__ flaglist,
                                 const int* __restrict__ flagcnt) {
    __shared__ float xsh[4 * 68];
    const int tid = threadIdx.x, w = tid >> 6, lane = tid & 63;
    const int cnt = *flagcnt;
    const float4* lut4 = reinterpret_cast<const float4*>(lut);

    for (int idx = blockIdx.x * 4 + w; idx < cnt; idx += 2048 * 4) {
        int tk = flaglist[idx];
        xsh[w * 68 + lane] = x[(long)(tk >> 12) * 262144 + (tk & 4095) + (long)lane * 4096];
        const float4* xf4 = reinterpret_cast<const float4*>(xsh + w * 68);

        float acc[16];
#pragma unroll
        for (int k = 0; k < 16; ++k) acc[k] = 0.f;

        for (int q = 0; q < 16; ++q) {
            float4 xf = xf4[q];                              // wave-broadcast
#pragma unroll
            for (int k = 0; k < 16; ++k) {
                float4 cf = lut4[(lane + 64 * k) * 16 + q];  // L2-hot gather
                acc[k] += xf.x * cf.x + xf.y * cf.y + xf.z * cf.z + xf.w * cf.w;  // verbatim
            }
        }
        float bv = 3.4e38f; int bj = 0;
#pragma unroll
        for (int k = 0; k < 16; ++k) {
            int j = lane + 64 * k;                           // ascending per lane
            float v = norms[j] - 2.f * acc[k];               // verbatim
            if (v < bv) { bv = v; bj = j; }
        }
#pragma unroll
        for (int m = 1; m <= 32; m <<= 1) {
            float ov = __shfl_xor(bv, m, 64);
            int   oj = __shfl_xor(bj, m, 64);
            if (ov < bv || (ov == bv && oj < bj)) { bv = ov; bj = oj; }
        }
        if (lane == 0) d_out[QX_OFF + tk] = (float)bj;
    }
}

// ---------------- epilogue: out = 2x - x_e (float4), per-block loss partial ----------------
__global__ void vq_epilogue_kernel(const float* __restrict__ x,
                                   const float* __restrict__ lut,
                                   float* __restrict__ d_out,
                                   float* __restrict__ partials) {
    __shared__ float cs[8192];                     // [d][128 tokens]
    __shared__ int qsh[128];
    __shared__ float wsum[4];
    const int tid = threadIdx.x;
    const int t0 = blockIdx.x * 128;
    const long xbase = (long)(t0 >> 12) * 262144 + (t0 & 4095);

    if (tid < 128) qsh[tid] = (int)d_out[QX_OFF + t0 + tid];
    __syncthreads();
    {
        int t = tid >> 1, half = tid & 1;
        int q = qsh[t];
        const float4* src = reinterpret_cast<const float4*>(lut + q * 64 + half * 32);
#pragma unroll
        for (int k = 0; k < 8; ++k) {
            float4 v = src[k];
            int dbase = half * 32 + k * 4;
            cs[(dbase + 0) * 128 + t] = v.x;
            cs[(dbase + 1) * 128 + t] = v.y;
            cs[(dbase + 2) * 128 + t] = v.z;
            cs[(dbase + 3) * 128 + t] = v.w;
        }
    }
    __syncthreads();

    float lsum = 0.f;
    {
        int t4 = (tid & 31) * 4, db = tid >> 5;
#pragma unroll
        for (int it = 0; it < 8; ++it) {
            int d = it * 8 + db;
            float4 xv = *reinterpret_cast<const float4*>(x + xbase + (long)d * 4096 + t4);
            float4 cv = *reinterpret_cast<const float4*>(cs + d * 128 + t4);
            float4 ov;
            ov.x = 2.f * xv.x - cv.x; ov.y = 2.f * xv.y - cv.y;
            ov.z = 2.f * xv.z - cv.z; ov.w = 2.f * xv.w - cv.w;
            *reinterpret_cast<float4*>(d_out + xbase + (long)d * 4096 + t4) = ov;
            float e0 = xv.x - cv.x, e1 = xv.y - cv.y, e2 = xv.z - cv.z, e3 = xv.w - cv.w;
            lsum += e0 * e0 + e1 * e1 + e2 * e2 + e3 * e3;
        }
    }
#pragma unroll
    for (int off = 32; off >= 1; off >>= 1)
        lsum += __shfl_down(lsum, off, 64);
    if ((tid & 63) == 0) wsum[tid >> 6] = lsum;
    __syncthreads();
    if (tid == 0)
        partials[blockIdx.x] = wsum[0] + wsum[1] + wsum[2] + wsum[3];
}

// ---------------- final loss reduce: 1024 partials -> scalar ----------------
__global__ void vq_loss_kernel(const float* __restrict__ partials,
                               float* __restrict__ d_out) {
    __shared__ float wsum[4];
    const int tid = threadIdx.x;
    float s = partials[tid] + partials[tid + 256] + partials[tid + 512] + partials[tid + 768];
#pragma unroll
    for (int off = 32; off >= 1; off >>= 1)
        s += __shfl_down(s, off, 64);
    if ((tid & 63) == 0) wsum[tid >> 6] = s;
    __syncthreads();
    if (tid == 0)
        d_out[LOSS_OFF] = (wsum[0] + wsum[1] + wsum[2] + wsum[3]) * (1.25f / 8388608.f);
}

extern "C" void kernel_launch(void* const* d_in, const int* in_sizes, int n_in,
                              void* d_out, int out_size, void* d_ws, size_t ws_size,
                              hipStream_t stream) {
    const float* x   = (const float*)d_in[0];   // [32,64,64,64] f32
    const float* lut = (const float*)d_in[1];   // [1024,64] f32
    float* out = (float*)d_out;
    char* ws = (char*)d_ws;
    float* norms    = (float*)ws;                        // 4 KB
    char*  lutbfB   = ws + 4096;                         // 256 KB bf16-split codebook
    int*   flagcnt  = (int*)(ws + 266240);
    int*   flaglist = (int*)(ws + 266256);               // worst case 512 KB
    float* partials = (float*)(ws + 790544);             // 4 KB epilogue loss partials

    vq_prep_kernel<<<4, 256, 0, stream>>>(lut, norms, lutbfB, flagcnt);
    vq_screen_kernel<<<512, 512, 34816, stream>>>(x, lutbfB, norms, out, flaglist, flagcnt);
    vq_rescan_kernel<<<2048, 256, 0, stream>>>(x, lut, norms, out, flaglist, flagcnt);
    vq_epilogue_kernel<<<1024, 256, 0, stream>>>(x, lut, out, partials);
    vq_loss_kernel<<<1, 256, 0, stream>>>(partials, out);
}